// Round 1
// baseline (34.773 us; speedup 1.0000x reference)
//
#include <hip/hip_runtime.h>
#include <hip/hip_bf16.h>

// HSTU positional encoder:
// out[i][d] = emb[i][d]*sqrt(D) + pos_weight[pos_ind(i)][d] + ts_weight[ts_ind(i)][d]
// Memory-bound gather+axpy. One block = 2 rows, float4 per lane.

__global__ __launch_bounds__(256) void hstu_pos_enc_kernel(
    const float4* __restrict__ emb4,      // [L, D/4]
    const float4* __restrict__ posw4,     // [P, D/4]
    const float4* __restrict__ tsw4,      // [NTB+1, D/4]
    const int*   __restrict__ seq_offsets, // [B+1]
    const int*   __restrict__ seq_lengths, // [B]
    const int*   __restrict__ num_targets, // [B]
    const int*   __restrict__ seq_ts,      // [L] int32 timestamps
    float4* __restrict__ out4,             // [L, D/4]
    int L, int D4, int B, int P, int NTB, float alpha)
{
    const int row  = blockIdx.x * 2 + (threadIdx.x >> 7);   // 2 rows per block
    const int lane = threadIdx.x & 127;                      // 0..127 -> D/4 slots
    if (row >= L || lane >= D4) return;

    // ---- per-row scalar work (redundant across 128 lanes; trivial cost) ----
    // find batch: seq_offsets[b] <= row < seq_offsets[b+1]
    int b = 0;
    while (b + 1 < B && seq_offsets[b + 1] <= row) ++b;

    const int off_b   = seq_offsets[b];
    const int rel_pos = row - off_b;

    int high_ind = max(seq_lengths[b], 0) - max(num_targets[b], 0);
    high_ind = max(high_ind, 0);

    // MAX_CONTEXTUAL_SEQ_LEN == 0 -> the "rel_pos < MCSL" branch never fires
    int pos_ind = (rel_pos < high_ind) ? rel_pos : high_ind;
    pos_ind = high_ind - pos_ind;
    pos_ind = min(pos_ind, P - 1);
    pos_ind = max(min(pos_ind, P - 1), 0);

    // time bucket
    const float qt = (float)seq_ts[seq_offsets[b + 1] - 1];
    const float tt = (float)seq_ts[row];
    float dt = fmaxf(qt - tt, 1e-6f) * (1.0f / 60.0f);   // TIME_DELTA=0, INCR=60
    dt = sqrtf(dt);                                       // TIME_BUCKET_SCALE=1
    int ts_ind = (int)dt;                                 // trunc, matches astype(int32)
    ts_ind = max(min(ts_ind, NTB), 0);                    // clip [0, NTB]

    // ---- vectorized body ----
    const float4 e = emb4[(long)row * D4 + lane];
    const float4 p = posw4[(long)pos_ind * D4 + lane];
    const float4 t = tsw4[(long)ts_ind * D4 + lane];

    float4 o;
    o.x = fmaf(e.x, alpha, p.x + t.x);
    o.y = fmaf(e.y, alpha, p.y + t.y);
    o.z = fmaf(e.z, alpha, p.z + t.z);
    o.w = fmaf(e.w, alpha, p.w + t.w);
    out4[(long)row * D4 + lane] = o;
}

extern "C" void kernel_launch(void* const* d_in, const int* in_sizes, int n_in,
                              void* d_out, int out_size, void* d_ws, size_t ws_size,
                              hipStream_t stream) {
    // setup_inputs order:
    // 0 max_seq_len (1), 1 seq_lengths (B), 2 seq_offsets (B+1),
    // 3 seq_embeddings (L*D), 4 num_targets (B), 5 seq_timestamps (L),
    // 6 pos_weight (P*D), 7 ts_weight ((NTB+1)*D)
    const int*   seq_lengths = (const int*)d_in[1];
    const int*   seq_offsets = (const int*)d_in[2];
    const float* emb         = (const float*)d_in[3];
    const int*   num_targets = (const int*)d_in[4];
    const int*   seq_ts      = (const int*)d_in[5];
    const float* posw        = (const float*)d_in[6];
    const float* tsw         = (const float*)d_in[7];

    const int B   = in_sizes[1];
    const int L   = in_sizes[5];
    const int D   = in_sizes[3] / L;
    const int D4  = D / 4;
    const int P   = in_sizes[6] / D;
    const int NTB = in_sizes[7] / D - 1;
    const float alpha = sqrtf((float)D);

    const int rows_per_block = 2;
    const int grid = (L + rows_per_block - 1) / rows_per_block;

    hstu_pos_enc_kernel<<<grid, 256, 0, stream>>>(
        (const float4*)emb, (const float4*)posw, (const float4*)tsw,
        seq_offsets, seq_lengths, num_targets, seq_ts,
        (float4*)d_out, L, D4, B, P, NTB, alpha);
}